// Round 5
// baseline (592.696 us; speedup 1.0000x reference)
//
#include <hip/hip_runtime.h>
#include <hip/hip_cooperative_groups.h>
#include <cstdint>

namespace cg = cooperative_groups;

// Problem constants (match reference)
#define Bn 8
#define Ln 4096
#define Dn 2048
#define Gn 32
#define GSn 64
static constexpr float EPS = 1e-5f;

// ---------------------------------------------------------------------------
// Phase A: per-(b,t,g) group means -> mT[b,g,t] (scan-friendly layout).
// ---------------------------------------------------------------------------
__device__ __forceinline__ void phaseA_rows(const float* __restrict__ x,
                                            float* __restrict__ mT,
                                            int row0, int rstride) {
    const int tid = threadIdx.x;
    for (int row = row0; row < Bn * Ln; row += rstride) {
        const float4* xr = reinterpret_cast<const float4*>(x + (size_t)row * Dn) + tid * 2;
        float4 a = xr[0], c = xr[1];
        float s = (a.x + a.y) + (a.z + a.w) + (c.x + c.y) + (c.z + c.w);
        s += __shfl_xor(s, 1);
        s += __shfl_xor(s, 2);
        s += __shfl_xor(s, 4);
        if ((tid & 7) == 0) {
            const int g = tid >> 3, b = row >> 12, t = row & (Ln - 1);
            mT[((size_t)(b * Gn + g)) * Ln + t] = s * (1.0f / (float)GSn);
        }
    }
}

// ---------------------------------------------------------------------------
// Phase B: one 256-thread block per (b,g) chain, 16 t/thread. Closed-form
// Welford via masked prefix sums. Writes mu/rstd in [b,t,g] (phase-C layout).
// mask (bool) and prev_count (int64) arrive as int32 from the harness.
// ---------------------------------------------------------------------------
__device__ __forceinline__ void phaseB_chain(const float* __restrict__ mT,
                                             const int* __restrict__ mask,
                                             const int* __restrict__ prev_count,
                                             const float* __restrict__ prev_mean,
                                             const float* __restrict__ prev_var,
                                             float* __restrict__ mu,
                                             float* __restrict__ rstd,
                                             float* __restrict__ out_count,
                                             float* __restrict__ out_mean,
                                             float* __restrict__ out_var,
                                             int bg) {
    const int b = bg >> 5;
    const int g = bg & 31;
    const int tid = threadIdx.x;
    const int t0 = tid * 16;

    float mv[16], km[16];
    const float4* mr = reinterpret_cast<const float4*>(mT + (size_t)bg * Ln + t0);
    const int4*   kr = reinterpret_cast<const int4*>(mask + b * Ln + t0);
#pragma unroll
    for (int i = 0; i < 4; ++i) {
        const float4 v = mr[i];
        const int4   k = kr[i];
        mv[4*i+0] = v.x; mv[4*i+1] = v.y; mv[4*i+2] = v.z; mv[4*i+3] = v.w;
        km[4*i+0] = k.x ? 1.f : 0.f; km[4*i+1] = k.y ? 1.f : 0.f;
        km[4*i+2] = k.z ? 1.f : 0.f; km[4*i+3] = k.w ? 1.f : 0.f;
    }

    float S = 0.f, Q = 0.f, P = 0.f;
#pragma unroll
    for (int i = 0; i < 16; ++i) { S += km[i]*mv[i]; Q += km[i]*mv[i]*mv[i]; P += km[i]; }

    // 64-lane wave inclusive scan, then 4-wave combine via LDS
    const int lane = tid & 63, wv = tid >> 6;
    float iS = S, iQ = Q, iP = P;
#pragma unroll
    for (int off = 1; off < 64; off <<= 1) {
        const float aS = __shfl_up(iS, off);
        const float aQ = __shfl_up(iQ, off);
        const float aP = __shfl_up(iP, off);
        if (lane >= off) { iS += aS; iQ += aQ; iP += aP; }
    }
    __shared__ float wS[4], wQ[4], wP[4];
    if (lane == 63) { wS[wv] = iS; wQ[wv] = iQ; wP[wv] = iP; }
    __syncthreads();
    float eS = iS - S, eQ = iQ - Q, eP = iP - P;   // exclusive prefix
#pragma unroll
    for (int w = 0; w < 3; ++w)
        if (wv > w) { eS += wS[w]; eQ += wQ[w]; eP += wP[w]; }

    const float c0  = (float)prev_count[b];
    const float mu0 = prev_mean[bg];
    const float v0  = prev_var[bg];
    const float A0  = c0 * mu0;
    const float M2b = v0 * fmaxf(c0, 1.f) + c0 * mu0 * mu0;

    float rS = eS, rQ = eQ, rP = eP;
#pragma unroll
    for (int i = 0; i < 16; ++i) {
        rS += km[i]*mv[i]; rQ += km[i]*mv[i]*mv[i]; rP += km[i];
        const float cs = fmaxf(c0 + rP, 1.f);
        const float rc = __builtin_amdgcn_rcpf(cs);
        const float mean = (A0 + rS) * rc;
        const float var  = (M2b + rQ) * rc - mean * mean;
        const size_t idx = ((size_t)b * Ln + (t0 + i)) * Gn + g;
        mu[idx]   = mean;
        rstd[idx] = rsqrtf(var + EPS);
        if (t0 + i == Ln - 1) {
            out_mean[bg] = mean;
            out_var[bg]  = (M2b + rQ) / cs - mean * mean;
            if (g == 0) out_count[b] = c0 + rP;
        }
    }
}

// ---------------------------------------------------------------------------
// Phase C: normalize + affine; mu/rstd in [b,t,g] (4 cache lines per row).
// ---------------------------------------------------------------------------
__device__ __forceinline__ void phaseC_rows(const float* __restrict__ x,
                                            const float* __restrict__ mu,
                                            const float* __restrict__ rstd,
                                            const float* __restrict__ w,
                                            const float* __restrict__ bias,
                                            float* __restrict__ y,
                                            int row0, int rstride) {
    const int tid = threadIdx.x;
    const int g = tid >> 3;
    const float4* wr = reinterpret_cast<const float4*>(w) + tid * 2;
    const float4* br = reinterpret_cast<const float4*>(bias) + tid * 2;
    const float4 wv0 = wr[0], wv1 = wr[1];
    const float4 bv0 = br[0], bv1 = br[1];
    for (int row = row0; row < Bn * Ln; row += rstride) {
        const size_t gi = (size_t)row * Gn + g;
        const float mean = mu[gi];
        const float rs   = rstd[gi];
        const float4* xr = reinterpret_cast<const float4*>(x + (size_t)row * Dn) + tid * 2;
        float4* yr = reinterpret_cast<float4*>(y + (size_t)row * Dn) + tid * 2;
        const float4 xv0 = xr[0];
        const float4 xv1 = xr[1];
        float4 o0, o1;
        o0.x = (xv0.x - mean) * rs * wv0.x + bv0.x;
        o0.y = (xv0.y - mean) * rs * wv0.y + bv0.y;
        o0.z = (xv0.z - mean) * rs * wv0.z + bv0.z;
        o0.w = (xv0.w - mean) * rs * wv0.w + bv0.w;
        o1.x = (xv1.x - mean) * rs * wv1.x + bv1.x;
        o1.y = (xv1.y - mean) * rs * wv1.y + bv1.y;
        o1.z = (xv1.z - mean) * rs * wv1.z + bv1.z;
        o1.w = (xv1.w - mean) * rs * wv1.w + bv1.w;
        yr[0] = o0;
        yr[1] = o1;
    }
}

// ---------------------------------------------------------------------------
// Fused cooperative kernel: A -> grid.sync -> B -> grid.sync -> C
// 1024 blocks x 256 threads (4 blocks/CU); launch_bounds caps VGPR at 128.
// ---------------------------------------------------------------------------
__global__ __launch_bounds__(256, 4) void fused(const float* __restrict__ x,
                                                const int* __restrict__ mask,
                                                const int* __restrict__ prev_count,
                                                const float* __restrict__ prev_mean,
                                                const float* __restrict__ prev_var,
                                                const float* __restrict__ weight,
                                                const float* __restrict__ bias,
                                                float* __restrict__ mT,
                                                float* __restrict__ mu,
                                                float* __restrict__ rstd,
                                                float* __restrict__ y,
                                                float* __restrict__ out_count,
                                                float* __restrict__ out_mean,
                                                float* __restrict__ out_var) {
    cg::grid_group grid = cg::this_grid();
    phaseA_rows(x, mT, blockIdx.x, gridDim.x);
    __threadfence();
    grid.sync();
    if (blockIdx.x < Bn * Gn)
        phaseB_chain(mT, mask, prev_count, prev_mean, prev_var,
                     mu, rstd, out_count, out_mean, out_var, blockIdx.x);
    __threadfence();
    grid.sync();
    phaseC_rows(x, mu, rstd, weight, bias, y, blockIdx.x, gridDim.x);
}

// ---------------------------------------------------------------------------
// Fallback (non-cooperative) kernels — same phases, 3 dispatches.
// ---------------------------------------------------------------------------
__global__ __launch_bounds__(256) void k1(const float* __restrict__ x, float* __restrict__ mT) {
    phaseA_rows(x, mT, blockIdx.x, gridDim.x);
}
__global__ __launch_bounds__(256) void k2(const float* __restrict__ mT,
                                          const int* __restrict__ mask,
                                          const int* __restrict__ prev_count,
                                          const float* __restrict__ prev_mean,
                                          const float* __restrict__ prev_var,
                                          float* __restrict__ mu,
                                          float* __restrict__ rstd,
                                          float* __restrict__ out_count,
                                          float* __restrict__ out_mean,
                                          float* __restrict__ out_var) {
    phaseB_chain(mT, mask, prev_count, prev_mean, prev_var,
                 mu, rstd, out_count, out_mean, out_var, blockIdx.x);
}
__global__ __launch_bounds__(256) void k3(const float* __restrict__ x,
                                          const float* __restrict__ mu,
                                          const float* __restrict__ rstd,
                                          const float* __restrict__ w,
                                          const float* __restrict__ bias,
                                          float* __restrict__ y) {
    phaseC_rows(x, mu, rstd, w, bias, y, blockIdx.x, gridDim.x);
}

// ---------------------------------------------------------------------------
extern "C" void kernel_launch(void* const* d_in, const int* in_sizes, int n_in,
                              void* d_out, int out_size, void* d_ws, size_t ws_size,
                              hipStream_t stream) {
    (void)in_sizes; (void)n_in; (void)out_size; (void)ws_size;

    const float* x          = (const float*)d_in[0];
    const int*   mask       = (const int*)d_in[1];     // bool pushed as int32
    const int*   prev_count = (const int*)d_in[2];     // int pushed as int32
    const float* prev_mean  = (const float*)d_in[3];
    const float* prev_var   = (const float*)d_in[4];
    const float* weight     = (const float*)d_in[5];
    const float* bias       = (const float*)d_in[6];

    float* out = (float*)d_out;
    float* y         = out;                                   // B*L*D
    float* out_count = out + (size_t)Bn * Ln * Dn;            // B
    float* out_mean  = out_count + Bn;                        // B*G
    float* out_var   = out_mean + (size_t)Bn * Gn;            // B*G

    // workspace: mT[b,g,t] | mu[b,t,g] | rstd[b,t,g], each B*L*G floats
    const size_t nBLG = (size_t)Bn * Ln * Gn;
    float* mT   = (float*)d_ws;
    float* mu   = mT + nBLG;
    float* rstd = mu + nBLG;

    void* kargs[] = { (void*)&x, (void*)&mask, (void*)&prev_count, (void*)&prev_mean,
                      (void*)&prev_var, (void*)&weight, (void*)&bias,
                      (void*)&mT, (void*)&mu, (void*)&rstd, (void*)&y,
                      (void*)&out_count, (void*)&out_mean, (void*)&out_var };
    dim3 grid(1024), block(256);
    hipError_t err = hipLaunchCooperativeKernel((const void*)fused, grid, block,
                                                kargs, 0, stream);
    if (err != hipSuccess) {
        // fallback: 3 plain dispatches (round-2 structure, best layouts)
        k1<<<2048, 256, 0, stream>>>(x, mT);
        k2<<<Bn * Gn, 256, 0, stream>>>(mT, mask, prev_count, prev_mean, prev_var,
                                        mu, rstd, out_count, out_mean, out_var);
        k3<<<2048, 256, 0, stream>>>(x, mu, rstd, weight, bias, y);
    }
}

// Round 6
// 443.353 us; speedup vs baseline: 1.3369x; 1.3369x over previous
//
#include <hip/hip_runtime.h>
#include <cstdint>

// Problem constants (match reference)
#define Bn 8
#define Ln 4096
#define Dn 2048
#define Gn 32
#define GSn 64
#define NBLK 1024                      // must equal resident-block capacity (4/CU x 256 CU)
static constexpr float EPS = 1e-5f;

// ---------------------------------------------------------------------------
// Lightweight grid barrier: leader atomically arrives (agent scope), spins on
// the counter with s_sleep. Counters live in d_ws and are zeroed by k_init at
// the head of every kernel_launch call (deterministic across graph replays).
// ---------------------------------------------------------------------------
__device__ __forceinline__ void gridbar(unsigned* ctr, unsigned target) {
    __syncthreads();
    if (threadIdx.x == 0) {
        __threadfence();   // publish this block's phase writes device-wide
        __hip_atomic_fetch_add(ctr, 1u, __ATOMIC_RELEASE, __HIP_MEMORY_SCOPE_AGENT);
        while (__hip_atomic_load(ctr, __ATOMIC_ACQUIRE, __HIP_MEMORY_SCOPE_AGENT) < target) {
            __builtin_amdgcn_s_sleep(2);
        }
    }
    __syncthreads();
}

__global__ __launch_bounds__(64) void k_init(unsigned* ctrs) {
    if (threadIdx.x < 2) ctrs[threadIdx.x] = 0u;
}

// ---------------------------------------------------------------------------
// Phase A: per-(b,t,g) group means -> m[b,t,g] (COALESCED 128-B row writes).
// ---------------------------------------------------------------------------
__device__ __forceinline__ void phaseA_rows(const float* __restrict__ x,
                                            float* __restrict__ m,
                                            int row0, int rstride) {
    const int tid = threadIdx.x;
    for (int row = row0; row < Bn * Ln; row += rstride) {
        const float4* xr = reinterpret_cast<const float4*>(x + (size_t)row * Dn) + tid * 2;
        float4 a = xr[0], c = xr[1];
        float s = (a.x + a.y) + (a.z + a.w) + (c.x + c.y) + (c.z + c.w);
        s += __shfl_xor(s, 1);
        s += __shfl_xor(s, 2);
        s += __shfl_xor(s, 4);
        if ((tid & 7) == 0) {
            const int g = tid >> 3;
            m[(size_t)row * Gn + g] = s * (1.0f / (float)GSn);
        }
    }
}

// ---------------------------------------------------------------------------
// Phase B: one block per (b,g) chain (blocks 0..255), 16 t/thread. Closed-form
// Welford via masked prefix sums. m read strided (L2/L3-served); mu/rstd
// written COALESCED in [b,g,t] float4.
// mask (bool) and prev_count (int64) arrive as int32 from the harness.
// ---------------------------------------------------------------------------
__device__ __forceinline__ void phaseB_chain(const float* __restrict__ m,
                                             const int* __restrict__ mask,
                                             const int* __restrict__ prev_count,
                                             const float* __restrict__ prev_mean,
                                             const float* __restrict__ prev_var,
                                             float* __restrict__ muT,
                                             float* __restrict__ rstdT,
                                             float* __restrict__ out_count,
                                             float* __restrict__ out_mean,
                                             float* __restrict__ out_var,
                                             int bg) {
    const int b = bg >> 5;
    const int g = bg & 31;
    const int tid = threadIdx.x;
    const int t0 = tid * 16;

    float mv[16], km[16];
    const int4* kr = reinterpret_cast<const int4*>(mask + b * Ln + t0);
#pragma unroll
    for (int i = 0; i < 16; ++i)
        mv[i] = m[((size_t)b * Ln + t0 + i) * Gn + g];
#pragma unroll
    for (int i = 0; i < 4; ++i) {
        const int4 k = kr[i];
        km[4*i+0] = k.x ? 1.f : 0.f; km[4*i+1] = k.y ? 1.f : 0.f;
        km[4*i+2] = k.z ? 1.f : 0.f; km[4*i+3] = k.w ? 1.f : 0.f;
    }

    float S = 0.f, Q = 0.f, P = 0.f;
#pragma unroll
    for (int i = 0; i < 16; ++i) { S += km[i]*mv[i]; Q += km[i]*mv[i]*mv[i]; P += km[i]; }

    // 64-lane wave inclusive scan, then 4-wave combine via LDS
    const int lane = tid & 63, wv = tid >> 6;
    float iS = S, iQ = Q, iP = P;
#pragma unroll
    for (int off = 1; off < 64; off <<= 1) {
        const float aS = __shfl_up(iS, off);
        const float aQ = __shfl_up(iQ, off);
        const float aP = __shfl_up(iP, off);
        if (lane >= off) { iS += aS; iQ += aQ; iP += aP; }
    }
    __shared__ float wS[4], wQ[4], wP[4];
    if (lane == 63) { wS[wv] = iS; wQ[wv] = iQ; wP[wv] = iP; }
    __syncthreads();
    float eS = iS - S, eQ = iQ - Q, eP = iP - P;   // exclusive prefix
#pragma unroll
    for (int w = 0; w < 3; ++w)
        if (wv > w) { eS += wS[w]; eQ += wQ[w]; eP += wP[w]; }

    const float c0  = (float)prev_count[b];
    const float mu0 = prev_mean[bg];
    const float v0  = prev_var[bg];
    const float A0  = c0 * mu0;
    const float M2b = v0 * fmaxf(c0, 1.f) + c0 * mu0 * mu0;

    float om[16], os[16];
    float rS = eS, rQ = eQ, rP = eP;
#pragma unroll
    for (int i = 0; i < 16; ++i) {
        rS += km[i]*mv[i]; rQ += km[i]*mv[i]*mv[i]; rP += km[i];
        const float cs = fmaxf(c0 + rP, 1.f);
        const float rc = __builtin_amdgcn_rcpf(cs);
        const float mean = (A0 + rS) * rc;
        const float var  = (M2b + rQ) * rc - mean * mean;
        om[i] = mean;
        os[i] = rsqrtf(var + EPS);
    }

    float4* mw = reinterpret_cast<float4*>(muT   + (size_t)bg * Ln + t0);
    float4* sw = reinterpret_cast<float4*>(rstdT + (size_t)bg * Ln + t0);
#pragma unroll
    for (int i = 0; i < 4; ++i) {
        mw[i] = make_float4(om[4*i+0], om[4*i+1], om[4*i+2], om[4*i+3]);
        sw[i] = make_float4(os[4*i+0], os[4*i+1], os[4*i+2], os[4*i+3]);
    }

    if (tid == 255) {                  // owns t = Ln-1
        const float cs = fmaxf(c0 + rP, 1.f);
        out_mean[bg] = om[15];
        out_var[bg]  = (M2b + rQ) / cs - om[15] * om[15];
        if (g == 0) out_count[b] = c0 + rP;
    }
}

// ---------------------------------------------------------------------------
// Phase C: normalize + affine. mu/rstd read transposed ([b,g,t]): 32 broadcast
// scalar loads per row, L2/L3-served (the small arrays are cache-hot).
// ---------------------------------------------------------------------------
__device__ __forceinline__ void phaseC_rows(const float* __restrict__ x,
                                            const float* __restrict__ muT,
                                            const float* __restrict__ rstdT,
                                            const float* __restrict__ w,
                                            const float* __restrict__ bias,
                                            float* __restrict__ y,
                                            int row0, int rstride) {
    const int tid = threadIdx.x;
    const int g = tid >> 3;
    const float4* wr = reinterpret_cast<const float4*>(w) + tid * 2;
    const float4* br = reinterpret_cast<const float4*>(bias) + tid * 2;
    const float4 wv0 = wr[0], wv1 = wr[1];
    const float4 bv0 = br[0], bv1 = br[1];
    for (int row = row0; row < Bn * Ln; row += rstride) {
        const int b = row >> 12;
        const int t = row & (Ln - 1);
        const size_t gi = ((size_t)(b * Gn + g)) * Ln + t;
        const float mean = muT[gi];
        const float rs   = rstdT[gi];
        const float4* xr = reinterpret_cast<const float4*>(x + (size_t)row * Dn) + tid * 2;
        float4* yr = reinterpret_cast<float4*>(y + (size_t)row * Dn) + tid * 2;
        const float4 xv0 = xr[0];
        const float4 xv1 = xr[1];
        float4 o0, o1;
        o0.x = (xv0.x - mean) * rs * wv0.x + bv0.x;
        o0.y = (xv0.y - mean) * rs * wv0.y + bv0.y;
        o0.z = (xv0.z - mean) * rs * wv0.z + bv0.z;
        o0.w = (xv0.w - mean) * rs * wv0.w + bv0.w;
        o1.x = (xv1.x - mean) * rs * wv1.x + bv1.x;
        o1.y = (xv1.y - mean) * rs * wv1.y + bv1.y;
        o1.z = (xv1.z - mean) * rs * wv1.z + bv1.z;
        o1.w = (xv1.w - mean) * rs * wv1.w + bv1.w;
        yr[0] = o0;
        yr[1] = o1;
    }
}

// ---------------------------------------------------------------------------
// Fused: A -> bar -> B -> bar -> C, one plain dispatch, custom barriers.
// 1024 blocks x 256 threads; __launch_bounds__(256,4) guarantees 4 blocks/CU
// residency (16 waves/CU, VGPR<=128) so the grid barrier cannot deadlock.
// ---------------------------------------------------------------------------
__global__ __launch_bounds__(256, 4) void fused(const float* __restrict__ x,
                                                const int* __restrict__ mask,
                                                const int* __restrict__ prev_count,
                                                const float* __restrict__ prev_mean,
                                                const float* __restrict__ prev_var,
                                                const float* __restrict__ weight,
                                                const float* __restrict__ bias,
                                                float* __restrict__ m,
                                                float* __restrict__ muT,
                                                float* __restrict__ rstdT,
                                                float* __restrict__ y,
                                                float* __restrict__ out_count,
                                                float* __restrict__ out_mean,
                                                float* __restrict__ out_var,
                                                unsigned* __restrict__ ctrs) {
    phaseA_rows(x, m, blockIdx.x, gridDim.x);
    gridbar(&ctrs[0], NBLK);
    if (blockIdx.x < Bn * Gn)
        phaseB_chain(m, mask, prev_count, prev_mean, prev_var,
                     muT, rstdT, out_count, out_mean, out_var, blockIdx.x);
    gridbar(&ctrs[1], NBLK);
    phaseC_rows(x, muT, rstdT, weight, bias, y, blockIdx.x, gridDim.x);
}

// ---------------------------------------------------------------------------
extern "C" void kernel_launch(void* const* d_in, const int* in_sizes, int n_in,
                              void* d_out, int out_size, void* d_ws, size_t ws_size,
                              hipStream_t stream) {
    (void)in_sizes; (void)n_in; (void)out_size; (void)ws_size;

    const float* x          = (const float*)d_in[0];
    const int*   mask       = (const int*)d_in[1];     // bool pushed as int32
    const int*   prev_count = (const int*)d_in[2];     // int pushed as int32
    const float* prev_mean  = (const float*)d_in[3];
    const float* prev_var   = (const float*)d_in[4];
    const float* weight     = (const float*)d_in[5];
    const float* bias       = (const float*)d_in[6];

    float* out = (float*)d_out;
    float* y         = out;                                   // B*L*D
    float* out_count = out + (size_t)Bn * Ln * Dn;            // B
    float* out_mean  = out_count + Bn;                        // B*G
    float* out_var   = out_mean + (size_t)Bn * Gn;            // B*G

    // workspace: m[b,t,g] | muT[b,g,t] | rstdT[b,g,t] | barrier counters
    const size_t nBLG = (size_t)Bn * Ln * Gn;
    float* m     = (float*)d_ws;
    float* muT   = m + nBLG;
    float* rstdT = muT + nBLG;
    unsigned* ctrs = (unsigned*)(rstdT + nBLG);

    k_init<<<1, 64, 0, stream>>>(ctrs);
    fused<<<NBLK, 256, 0, stream>>>(x, mask, prev_count, prev_mean, prev_var,
                                    weight, bias, m, muT, rstdT, y,
                                    out_count, out_mean, out_var, ctrs);
}

// Round 7
// 354.188 us; speedup vs baseline: 1.6734x; 1.2517x over previous
//
#include <hip/hip_runtime.h>
#include <cstdint>

// Problem constants (match reference)
#define Bn 8
#define Ln 4096
#define Dn 2048
#define Gn 32
#define GSn 64
#define NBLK 1024                      // must equal resident-block capacity (4/CU x 256 CU)
static constexpr float EPS = 1e-5f;

// ---------------------------------------------------------------------------
// Grid barrier. Arrival: release RMW (one L2 writeback publishes this block's
// writes). Poll: RELAXED agent-scope atomic loads — these bypass the
// non-coherent per-XCD L2s (so no stale spin) but do NOT emit the L2
// invalidate that ACQUIRE adds. Round-6 lesson: acquire-in-loop invalidated
// L2 thousands of times/barrier and collapsed phase BW to 1.3 TB/s.
// One acquire after spin-exit establishes ordering.
// ---------------------------------------------------------------------------
__device__ __forceinline__ void gridbar(unsigned* ctr, unsigned target) {
    __syncthreads();
    if (threadIdx.x == 0) {
        __hip_atomic_fetch_add(ctr, 1u, __ATOMIC_ACQ_REL, __HIP_MEMORY_SCOPE_AGENT);
        while (__hip_atomic_load(ctr, __ATOMIC_RELAXED, __HIP_MEMORY_SCOPE_AGENT) < target) {
            __builtin_amdgcn_s_sleep(4);
        }
        (void)__hip_atomic_load(ctr, __ATOMIC_ACQUIRE, __HIP_MEMORY_SCOPE_AGENT);
    }
    __syncthreads();
}

__global__ __launch_bounds__(64) void k_init(unsigned* ctrs) {
    if (threadIdx.x < 2) ctrs[threadIdx.x] = 0u;
}

// ---------------------------------------------------------------------------
// Phase A: per-(b,t,g) group means -> m[b,t,g] (COALESCED 128-B row writes).
// ---------------------------------------------------------------------------
__device__ __forceinline__ void phaseA_rows(const float* __restrict__ x,
                                            float* __restrict__ m,
                                            int row0, int rstride) {
    const int tid = threadIdx.x;
    for (int row = row0; row < Bn * Ln; row += rstride) {
        const float4* xr = reinterpret_cast<const float4*>(x + (size_t)row * Dn) + tid * 2;
        float4 a = xr[0], c = xr[1];
        float s = (a.x + a.y) + (a.z + a.w) + (c.x + c.y) + (c.z + c.w);
        s += __shfl_xor(s, 1);
        s += __shfl_xor(s, 2);
        s += __shfl_xor(s, 4);
        if ((tid & 7) == 0) {
            const int g = tid >> 3;
            m[(size_t)row * Gn + g] = s * (1.0f / (float)GSn);
        }
    }
}

// ---------------------------------------------------------------------------
// Phase B: one block per (b,g) chain (blocks 0..255), 16 t/thread. Closed-form
// Welford via masked prefix sums. m read strided (L2/L3-served); mu/rstd
// written COALESCED in [b,g,t] float4.
// mask (bool) and prev_count (int64) arrive as int32 from the harness.
// ---------------------------------------------------------------------------
__device__ __forceinline__ void phaseB_chain(const float* __restrict__ m,
                                             const int* __restrict__ mask,
                                             const int* __restrict__ prev_count,
                                             const float* __restrict__ prev_mean,
                                             const float* __restrict__ prev_var,
                                             float* __restrict__ muT,
                                             float* __restrict__ rstdT,
                                             float* __restrict__ out_count,
                                             float* __restrict__ out_mean,
                                             float* __restrict__ out_var,
                                             int bg) {
    const int b = bg >> 5;
    const int g = bg & 31;
    const int tid = threadIdx.x;
    const int t0 = tid * 16;

    float mv[16], km[16];
    const int4* kr = reinterpret_cast<const int4*>(mask + b * Ln + t0);
#pragma unroll
    for (int i = 0; i < 16; ++i)
        mv[i] = m[((size_t)b * Ln + t0 + i) * Gn + g];
#pragma unroll
    for (int i = 0; i < 4; ++i) {
        const int4 k = kr[i];
        km[4*i+0] = k.x ? 1.f : 0.f; km[4*i+1] = k.y ? 1.f : 0.f;
        km[4*i+2] = k.z ? 1.f : 0.f; km[4*i+3] = k.w ? 1.f : 0.f;
    }

    float S = 0.f, Q = 0.f, P = 0.f;
#pragma unroll
    for (int i = 0; i < 16; ++i) { S += km[i]*mv[i]; Q += km[i]*mv[i]*mv[i]; P += km[i]; }

    // 64-lane wave inclusive scan, then 4-wave combine via LDS
    const int lane = tid & 63, wv = tid >> 6;
    float iS = S, iQ = Q, iP = P;
#pragma unroll
    for (int off = 1; off < 64; off <<= 1) {
        const float aS = __shfl_up(iS, off);
        const float aQ = __shfl_up(iQ, off);
        const float aP = __shfl_up(iP, off);
        if (lane >= off) { iS += aS; iQ += aQ; iP += aP; }
    }
    __shared__ float wS[4], wQ[4], wP[4];
    if (lane == 63) { wS[wv] = iS; wQ[wv] = iQ; wP[wv] = iP; }
    __syncthreads();
    float eS = iS - S, eQ = iQ - Q, eP = iP - P;   // exclusive prefix
#pragma unroll
    for (int w = 0; w < 3; ++w)
        if (wv > w) { eS += wS[w]; eQ += wQ[w]; eP += wP[w]; }

    const float c0  = (float)prev_count[b];
    const float mu0 = prev_mean[bg];
    const float v0  = prev_var[bg];
    const float A0  = c0 * mu0;
    const float M2b = v0 * fmaxf(c0, 1.f) + c0 * mu0 * mu0;

    float om[16], os[16];
    float rS = eS, rQ = eQ, rP = eP;
#pragma unroll
    for (int i = 0; i < 16; ++i) {
        rS += km[i]*mv[i]; rQ += km[i]*mv[i]*mv[i]; rP += km[i];
        const float cs = fmaxf(c0 + rP, 1.f);
        const float rc = __builtin_amdgcn_rcpf(cs);
        const float mean = (A0 + rS) * rc;
        const float var  = (M2b + rQ) * rc - mean * mean;
        om[i] = mean;
        os[i] = rsqrtf(var + EPS);
    }

    float4* mw = reinterpret_cast<float4*>(muT   + (size_t)bg * Ln + t0);
    float4* sw = reinterpret_cast<float4*>(rstdT + (size_t)bg * Ln + t0);
#pragma unroll
    for (int i = 0; i < 4; ++i) {
        mw[i] = make_float4(om[4*i+0], om[4*i+1], om[4*i+2], om[4*i+3]);
        sw[i] = make_float4(os[4*i+0], os[4*i+1], os[4*i+2], os[4*i+3]);
    }

    if (tid == 255) {                  // owns t = Ln-1
        const float cs = fmaxf(c0 + rP, 1.f);
        out_mean[bg] = om[15];
        out_var[bg]  = (M2b + rQ) / cs - om[15] * om[15];
        if (g == 0) out_count[b] = c0 + rP;
    }
}

// ---------------------------------------------------------------------------
// Phase C: normalize + affine. mu/rstd read transposed ([b,g,t]): 32 broadcast
// scalar loads per row, L2/L3-served (the small arrays are cache-hot).
// ---------------------------------------------------------------------------
__device__ __forceinline__ void phaseC_rows(const float* __restrict__ x,
                                            const float* __restrict__ muT,
                                            const float* __restrict__ rstdT,
                                            const float* __restrict__ w,
                                            const float* __restrict__ bias,
                                            float* __restrict__ y,
                                            int row0, int rstride) {
    const int tid = threadIdx.x;
    const int g = tid >> 3;
    const float4* wr = reinterpret_cast<const float4*>(w) + tid * 2;
    const float4* br = reinterpret_cast<const float4*>(bias) + tid * 2;
    const float4 wv0 = wr[0], wv1 = wr[1];
    const float4 bv0 = br[0], bv1 = br[1];
    for (int row = row0; row < Bn * Ln; row += rstride) {
        const int b = row >> 12;
        const int t = row & (Ln - 1);
        const size_t gi = ((size_t)(b * Gn + g)) * Ln + t;
        const float mean = muT[gi];
        const float rs   = rstdT[gi];
        const float4* xr = reinterpret_cast<const float4*>(x + (size_t)row * Dn) + tid * 2;
        float4* yr = reinterpret_cast<float4*>(y + (size_t)row * Dn) + tid * 2;
        const float4 xv0 = xr[0];
        const float4 xv1 = xr[1];
        float4 o0, o1;
        o0.x = (xv0.x - mean) * rs * wv0.x + bv0.x;
        o0.y = (xv0.y - mean) * rs * wv0.y + bv0.y;
        o0.z = (xv0.z - mean) * rs * wv0.z + bv0.z;
        o0.w = (xv0.w - mean) * rs * wv0.w + bv0.w;
        o1.x = (xv1.x - mean) * rs * wv1.x + bv1.x;
        o1.y = (xv1.y - mean) * rs * wv1.y + bv1.y;
        o1.z = (xv1.z - mean) * rs * wv1.z + bv1.z;
        o1.w = (xv1.w - mean) * rs * wv1.w + bv1.w;
        yr[0] = o0;
        yr[1] = o1;
    }
}

// ---------------------------------------------------------------------------
// Fused: A -> bar -> B -> bar -> C, one plain dispatch, custom barriers.
// 1024 blocks x 256 threads; __launch_bounds__(256,4) guarantees 4 blocks/CU
// residency (16 waves/CU, VGPR<=64/wave at this bound) so the grid barrier
// cannot deadlock.
// ---------------------------------------------------------------------------
__global__ __launch_bounds__(256, 4) void fused(const float* __restrict__ x,
                                                const int* __restrict__ mask,
                                                const int* __restrict__ prev_count,
                                                const float* __restrict__ prev_mean,
                                                const float* __restrict__ prev_var,
                                                const float* __restrict__ weight,
                                                const float* __restrict__ bias,
                                                float* __restrict__ m,
                                                float* __restrict__ muT,
                                                float* __restrict__ rstdT,
                                                float* __restrict__ y,
                                                float* __restrict__ out_count,
                                                float* __restrict__ out_mean,
                                                float* __restrict__ out_var,
                                                unsigned* __restrict__ ctrs) {
    phaseA_rows(x, m, blockIdx.x, gridDim.x);
    gridbar(&ctrs[0], NBLK);
    if (blockIdx.x < Bn * Gn)
        phaseB_chain(m, mask, prev_count, prev_mean, prev_var,
                     muT, rstdT, out_count, out_mean, out_var, blockIdx.x);
    gridbar(&ctrs[1], NBLK);
    phaseC_rows(x, muT, rstdT, weight, bias, y, blockIdx.x, gridDim.x);
}

// ---------------------------------------------------------------------------
extern "C" void kernel_launch(void* const* d_in, const int* in_sizes, int n_in,
                              void* d_out, int out_size, void* d_ws, size_t ws_size,
                              hipStream_t stream) {
    (void)in_sizes; (void)n_in; (void)out_size; (void)ws_size;

    const float* x          = (const float*)d_in[0];
    const int*   mask       = (const int*)d_in[1];     // bool pushed as int32
    const int*   prev_count = (const int*)d_in[2];     // int pushed as int32
    const float* prev_mean  = (const float*)d_in[3];
    const float* prev_var   = (const float*)d_in[4];
    const float* weight     = (const float*)d_in[5];
    const float* bias       = (const float*)d_in[6];

    float* out = (float*)d_out;
    float* y         = out;                                   // B*L*D
    float* out_count = out + (size_t)Bn * Ln * Dn;            // B
    float* out_mean  = out_count + Bn;                        // B*G
    float* out_var   = out_mean + (size_t)Bn * Gn;            // B*G

    // workspace: m[b,t,g] | muT[b,g,t] | rstdT[b,g,t] | barrier counters
    const size_t nBLG = (size_t)Bn * Ln * Gn;
    float* m     = (float*)d_ws;
    float* muT   = m + nBLG;
    float* rstdT = muT + nBLG;
    unsigned* ctrs = (unsigned*)(rstdT + nBLG);

    k_init<<<1, 64, 0, stream>>>(ctrs);
    fused<<<NBLK, 256, 0, stream>>>(x, mask, prev_count, prev_mean, prev_var,
                                    weight, bias, m, muT, rstdT, y,
                                    out_count, out_mean, out_var, ctrs);
}

// Round 8
// 108.714 us; speedup vs baseline: 5.4519x; 3.2580x over previous
//
#include <hip/hip_runtime.h>
#include <cstdint>

// Problem constants (match reference)
#define Bn 8
#define Ln 4096
#define Dn 2048
#define Gn 32
#define GSn 64
#define ROWS 64                 // rows (timesteps) per tile: 1024 threads = 64 rows x 16 lanes
#define NT (Ln / ROWS)          // 64 tiles per chain
static constexpr float EPS = 1e-5f;

// ---------------------------------------------------------------------------
// One block per (b,g) chain. Per tile of 64 timesteps:
//   load x-slab (float4/thread, 256B/row segments) [prefetched one tile ahead]
//   row group-sum via 4x shfl_xor within 16-lane groups
//   block-inclusive scan of masked (S,Q,P) over rows: in-wave scan (4 rows) +
//     wave0 combine of 16 wave totals via LDS (2 barriers/tile)
//   closed-form Welford: mean_t=(c0*mu0+S_t)/cs, var_t=(v0*max(c0,1)+c0*mu0^2+Q_t)/cs - mean_t^2
//   normalize in registers, store y.
// x read once, y written once; no workspace, no grid sync.
// mask (bool) and prev_count (int64) are pushed by the harness as int32.
// ---------------------------------------------------------------------------
__global__ __launch_bounds__(1024, 1) void fused_chain(
    const float* __restrict__ x,
    const int* __restrict__ mask,
    const int* __restrict__ prev_count,
    const float* __restrict__ prev_mean,
    const float* __restrict__ prev_var,
    const float* __restrict__ weight,
    const float* __restrict__ bias,
    float* __restrict__ y,
    float* __restrict__ out_count,
    float* __restrict__ out_mean,
    float* __restrict__ out_var)
{
    const int bg  = blockIdx.x;      // b*G + g
    const int b   = bg >> 5;
    const int g   = bg & 31;
    const int tid = threadIdx.x;
    const int r    = tid >> 4;       // row-in-tile 0..63
    const int k    = tid & 15;       // 16 lanes per row, float4 each = 64 elems
    const int lane = tid & 63;
    const int wv   = tid >> 6;       // wave 0..15

    const size_t xbase = (size_t)b * Ln * Dn + g * GSn + k * 4;
    const int    mbase = b * Ln;

    const float4 wv4 = *reinterpret_cast<const float4*>(weight + g * GSn + k * 4);
    const float4 bv4 = *reinterpret_cast<const float4*>(bias   + g * GSn + k * 4);

    const float c0  = (float)prev_count[b];
    const float mu0 = prev_mean[bg];
    const float v0  = prev_var[bg];
    const float A0  = c0 * mu0;
    const float M2b = v0 * fmaxf(c0, 1.f) + c0 * mu0 * mu0;

    __shared__ float wT[3][16];      // per-wave inclusive totals
    __shared__ float eT[3][16];      // per-wave exclusive prefixes
    __shared__ float tT[3];          // tile totals

    float carS = 0.f, carQ = 0.f, carP = 0.f;   // carry across tiles (uniform)

    // prefetch tile 0
    float4 xc = *reinterpret_cast<const float4*>(x + xbase + (size_t)r * Dn);
    float  mkc = mask[mbase + r] ? 1.f : 0.f;

    for (int it = 0; it < NT; ++it) {
        // ---- prefetch next tile (issued before the barriers; hides HBM latency)
        const int rgn = (it + 1 < NT) ? ((it + 1) * ROWS + r) : r;
        float4 xn = *reinterpret_cast<const float4*>(x + xbase + (size_t)rgn * Dn);
        float  mkn = mask[mbase + rgn] ? 1.f : 0.f;

        // ---- row group-sum (64 elems = 16 lanes x float4)
        float s = (xc.x + xc.y) + (xc.z + xc.w);
        s += __shfl_xor(s, 1);
        s += __shfl_xor(s, 2);
        s += __shfl_xor(s, 4);
        s += __shfl_xor(s, 8);
        const float m = s * (1.f / (float)GSn);

        const float aS = mkc * m;
        const float aQ = mkc * m * m;
        const float aP = mkc;

        // ---- in-wave inclusive scan over the wave's 4 rows (16-lane groups)
        float iS = aS, iQ = aQ, iP = aP;
        {
            float u0 = __shfl_up(iS, 16), u1 = __shfl_up(iQ, 16), u2 = __shfl_up(iP, 16);
            if (lane >= 16) { iS += u0; iQ += u1; iP += u2; }
            u0 = __shfl_up(iS, 32); u1 = __shfl_up(iQ, 32); u2 = __shfl_up(iP, 32);
            if (lane >= 32) { iS += u0; iQ += u1; iP += u2; }
        }
        if (lane == 63) { wT[0][wv] = iS; wT[1][wv] = iQ; wT[2][wv] = iP; }
        __syncthreads();

        // ---- wave0: scan the 16 wave totals
        if (wv == 0 && lane < 16) {
            const float vS = wT[0][lane], vQ = wT[1][lane], vP = wT[2][lane];
            float jS = vS, jQ = vQ, jP = vP;
#pragma unroll
            for (int off = 1; off < 16; off <<= 1) {
                const float u0 = __shfl_up(jS, off, 16);
                const float u1 = __shfl_up(jQ, off, 16);
                const float u2 = __shfl_up(jP, off, 16);
                if (lane >= off) { jS += u0; jQ += u1; jP += u2; }
            }
            eT[0][lane] = jS - vS; eT[1][lane] = jQ - vQ; eT[2][lane] = jP - vP;
            if (lane == 15) { tT[0] = jS; tT[1] = jQ; tT[2] = jP; }
        }
        __syncthreads();

        // ---- inclusive prefix for this row, closed-form Welford
        const float S = carS + eT[0][wv] + iS;
        const float Q = carQ + eT[1][wv] + iQ;
        const float P = carP + eT[2][wv] + iP;
        const float cs = fmaxf(c0 + P, 1.f);
        const float rc = __builtin_amdgcn_rcpf(cs);
        const float mean = (A0 + S) * rc;
        const float var  = (M2b + Q) * rc - mean * mean;
        const float rs   = rsqrtf(var + EPS);

        // ---- normalize + affine, store
        float4 o;
        o.x = (xc.x - mean) * rs * wv4.x + bv4.x;
        o.y = (xc.y - mean) * rs * wv4.y + bv4.y;
        o.z = (xc.z - mean) * rs * wv4.z + bv4.z;
        o.w = (xc.w - mean) * rs * wv4.w + bv4.w;
        *reinterpret_cast<float4*>(y + xbase + (size_t)(it * ROWS + r) * Dn) = o;

        // ---- advance carry (uniform across block), rotate prefetch
        carS += tT[0]; carQ += tT[1]; carP += tT[2];
        xc = xn; mkc = mkn;
    }

    if (tid == 0) {
        const float c  = c0 + carP;
        const float cs = fmaxf(c, 1.f);
        const float mean = (A0 + carS) / cs;
        out_mean[bg] = mean;
        out_var[bg]  = (M2b + carQ) / cs - mean * mean;
        if (g == 0) out_count[b] = c;
    }
}

// ---------------------------------------------------------------------------
extern "C" void kernel_launch(void* const* d_in, const int* in_sizes, int n_in,
                              void* d_out, int out_size, void* d_ws, size_t ws_size,
                              hipStream_t stream) {
    (void)in_sizes; (void)n_in; (void)out_size; (void)d_ws; (void)ws_size;

    const float* x          = (const float*)d_in[0];
    const int*   mask       = (const int*)d_in[1];     // bool pushed as int32
    const int*   prev_count = (const int*)d_in[2];     // int pushed as int32
    const float* prev_mean  = (const float*)d_in[3];
    const float* prev_var   = (const float*)d_in[4];
    const float* weight     = (const float*)d_in[5];
    const float* bias       = (const float*)d_in[6];

    float* out = (float*)d_out;
    float* y         = out;                                   // B*L*D
    float* out_count = out + (size_t)Bn * Ln * Dn;            // B
    float* out_mean  = out_count + Bn;                        // B*G
    float* out_var   = out_mean + (size_t)Bn * Gn;            // B*G

    fused_chain<<<Bn * Gn, 1024, 0, stream>>>(x, mask, prev_count, prev_mean,
                                              prev_var, weight, bias, y,
                                              out_count, out_mean, out_var);
}